// Round 4
// baseline (78.069 us; speedup 1.0000x reference)
//
#include <hip/hip_runtime.h>

#define H       128
#define NPTS    512
#define NBATCH  4
#define BLOCK   256
#define WAVES   4
#define PW      8

// ---- distance->magnitude table ----
// t = log2(dist_safe), dist_safe in [1e-4, 50] (the reference's clip range).
// TSAMP samples t_k = T0 + k*TRANGE/TIVL, k = 0..TIVL; TIVL intervals.
#define TSAMP   8192
#define TIVL    8191
#define T0      (-13.2877123795f)
#define TRANGE  (18.9315685693f)

__device__ __forceinline__ float fast_rcp(float x) { return __builtin_amdgcn_rcpf(x); }

__device__ __forceinline__ float silu_f(float x) {
    float e = __expf(-x);
    return x * fast_rcp(1.0f + e);
}

__device__ __forceinline__ float bcast_lane(float v, int src) {
    // v_readlane_b32: wave-uniform broadcast via SGPR, does NOT touch the LDS pipe
    return __uint_as_float(__builtin_amdgcn_readlane(__float_as_uint(v), src));
}

// ============================================================================
// Kernel 1: build magnitude table. 256 blocks x 256 thr; wave owns 8 samples.
// Register-resident layer-1 (lane L holds h1[ch=L] and h1[ch=L+64] for the
// wave's 8 samples); layer-2 broadcasts h1[j] via v_readlane (VALU, not LDS)
// and reads W2 row j as one coalesced b64 per lane per j (L2-resident).
// NO LDS, NO barriers.  tab duplicated: tab[2k]=g_k, tab[2k+1]=g_{k+1}.
// ============================================================================
__global__ __launch_bounds__(BLOCK) void build_mag_table(
    const float* __restrict__ W1, const float* __restrict__ b1,
    const float* __restrict__ W2, const float* __restrict__ b2,
    const float* __restrict__ W3, const float* __restrict__ b3,
    float* __restrict__ tab)
{
    const int tid  = threadIdx.x;
    const int lane = tid & 63;
    const int w    = tid >> 6;
    const int base = blockIdx.x * (WAVES * PW) + w * PW;   // 256*32 = 8192 = TSAMP

    // ---- sample geometry (redundant per lane — cheap) ----
    float d8[PW], in8[PW];
    #pragma unroll
    for (int p = 0; p < PW; ++p) {
        float t  = fmaf((float)(base + p), TRANGE / (float)TIVL, T0);
        float d  = exp2f(t);
        float ds = fminf(fmaxf(d, 1e-4f), 50.0f);
        d8[p]  = ds;
        in8[p] = 1.0f / ds;
    }

    // ---- layer 1: lane owns channels (lane, lane+64); weights straight from L2 ----
    const float wa0 = W1[lane],      wb0 = W1[H + lane],      bb0 = b1[lane];
    const float wa1 = W1[lane + 64], wb1 = W1[H + lane + 64], bb1 = b1[lane + 64];
    float ha[PW], hb[PW];
    #pragma unroll
    for (int p = 0; p < PW; ++p) {
        ha[p] = silu_f(fmaf(d8[p], wa0, fmaf(in8[p], wb0, bb0)));
        hb[p] = silu_f(fmaf(d8[p], wa1, fmaf(in8[p], wb1, bb1)));
    }

    // ---- layer 2: lane owns output channels k0, k0+1 ----
    const int k0 = 2 * lane;
    float acc0[PW], acc1[PW];
    #pragma unroll
    for (int p = 0; p < PW; ++p) { acc0[p] = 0.f; acc1[p] = 0.f; }

    const float2* w2v = (const float2*)W2;   // w2v[j*64 + lane] = (W2[j][2l], W2[j][2l+1])

    #pragma unroll 16
    for (int j = 0; j < 64; ++j) {
        const float2 ww = w2v[j * 64 + lane];          // coalesced row j, L2-hot
        #pragma unroll
        for (int p = 0; p < PW; ++p) {
            const float hv = bcast_lane(ha[p], j);     // h1[j][p]
            acc0[p] = fmaf(hv, ww.x, acc0[p]);
            acc1[p] = fmaf(hv, ww.y, acc1[p]);
        }
    }
    #pragma unroll 16
    for (int j = 0; j < 64; ++j) {
        const float2 ww = w2v[(j + 64) * 64 + lane];   // rows 64..127
        #pragma unroll
        for (int p = 0; p < PW; ++p) {
            const float hv = bcast_lane(hb[p], j);     // h1[j+64][p]
            acc0[p] = fmaf(hv, ww.x, acc0[p]);
            acc1[p] = fmaf(hv, ww.y, acc1[p]);
        }
    }

    // ---- layer 3 + full-wave butterfly (sums all 128 channels) ----
    const float b20 = b2[k0], b21 = b2[k0 + 1];
    const float w30 = W3[k0], w31 = W3[k0 + 1];
    float part[PW];
    #pragma unroll
    for (int p = 0; p < PW; ++p)
        part[p] = silu_f(acc0[p] + b20) * w30 + silu_f(acc1[p] + b21) * w31;

    #pragma unroll
    for (int off = 32; off >= 1; off >>= 1) {
        #pragma unroll
        for (int p = 0; p < PW; ++p)
            part[p] += __shfl_xor(part[p], off);
    }

    if (lane == 0) {
        const float b3v = b3[0];
        #pragma unroll
        for (int p = 0; p < PW; ++p) {
            const int k = base + p;                 // 0..TIVL
            const float g = part[p] + b3v;
            if (k < TIVL) tab[2 * k] = g;           // tab2[k].x
            if (k >= 1)   tab[2 * k - 1] = g;       // tab2[k-1].y
        }
    }
}

// ============================================================================
// Kernel 2: forces. 512 blocks x 256 thr; one ROW per wave (64 lanes x 8 j).
// ============================================================================
__global__ __launch_bounds__(BLOCK) void eval_forces(
    const float* __restrict__ pos, const float* __restrict__ tab,
    float* __restrict__ out)
{
    __shared__ float poss[NPTS * 3];

    const int tid  = threadIdx.x;
    const int lane = tid & 63;
    const int w    = tid >> 6;
    const int row  = blockIdx.x * WAVES + w;     // 512*4 = 2048 rows
    const int b    = row >> 9;                   // same for all 4 waves (4 | 512)
    const int i    = row & (NPTS - 1);

    {
        const float4* src = (const float4*)(pos + b * NPTS * 3);
        float4* dst = (float4*)poss;
        for (int r = tid; r < NPTS * 3 / 4; r += BLOCK) dst[r] = src[r];
    }
    __syncthreads();

    const float pix = poss[3 * i + 0];
    const float piy = poss[3 * i + 1];
    const float piz = poss[3 * i + 2];

    const float INVH = (float)TIVL / TRANGE;
    const float XOFF = -T0 * ((float)TIVL / TRANGE);
    const float2* tab2 = (const float2*)tab;

    float fx = 0.f, fy = 0.f, fz = 0.f;

    #pragma unroll
    for (int k = 0; k < NPTS / 64; ++k) {
        const int j = lane + 64 * k;
        const float dx = pix - poss[3 * j + 0];
        const float dy = piy - poss[3 * j + 1];
        const float dz = piz - poss[3 * j + 2];
        const float s  = fmaf(dx, dx, fmaf(dy, dy, dz * dz));
        const bool ok  = (s > 0.0f) && (j != i);
        const float rs = __builtin_amdgcn_rsqf(fmaxf(s, 1e-30f));
        const float d  = s * rs;
        const float ds = fminf(fmaxf(d, 1e-4f), 50.0f);
        float x = fmaf(__log2f(ds), INVH, XOFF);
        x = fminf(fmaxf(x, 0.0f), (float)TIVL - 0.001f);
        const int   kk = (int)x;
        const float fr = x - (float)kk;
        const float2 g = tab2[kk];
        const float mag = fmaf(fr, g.y - g.x, g.x);
        const float f   = ok ? mag * fminf(rs, 1e6f) : 0.0f;
        fx = fmaf(f, dx, fx);
        fy = fmaf(f, dy, fy);
        fz = fmaf(f, dz, fz);
    }

    #pragma unroll
    for (int off = 32; off >= 1; off >>= 1) {
        fx += __shfl_xor(fx, off);
        fy += __shfl_xor(fy, off);
        fz += __shfl_xor(fz, off);
    }
    if (lane == 0) {
        out[row * 3 + 0] = fx;
        out[row * 3 + 1] = fy;
        out[row * 3 + 2] = fz;
    }
}

extern "C" void kernel_launch(void* const* d_in, const int* in_sizes, int n_in,
                              void* d_out, int out_size, void* d_ws, size_t ws_size,
                              hipStream_t stream) {
    const float* pos = (const float*)d_in[0];
    const float* W1  = (const float*)d_in[1];
    const float* b1  = (const float*)d_in[2];
    const float* W2  = (const float*)d_in[3];
    const float* b2  = (const float*)d_in[4];
    const float* W3  = (const float*)d_in[5];
    const float* b3  = (const float*)d_in[6];
    float* out = (float*)d_out;
    float* tab = (float*)d_ws;

    hipLaunchKernelGGL(build_mag_table, dim3(TSAMP / (WAVES * PW)), dim3(BLOCK), 0, stream,
                       W1, b1, W2, b2, W3, b3, tab);
    hipLaunchKernelGGL(eval_forces, dim3(NBATCH * NPTS / WAVES), dim3(BLOCK), 0, stream,
                       pos, tab, out);
}